// Round 1
// baseline (764.878 us; speedup 1.0000x reference)
//
#include <hip/hip_runtime.h>
#include <math.h>

// ---------------------------------------------------------------------------
// Sizes (compile-time constants from the reference)
// ---------------------------------------------------------------------------
#define NB   512          // batch
#define TT   60           // timesteps
#define FF   5            // input features
#define HH   128          // hidden
#define G4   512          // 4*H gates
#define NN   2500         // neurons
#define KK   50           // conn per neuron

// group boundaries
#define O0 800
#define O1 1500
#define O2 2100

// workspace layout (float offsets)
#define OFF_WHH0T 0                    // 128*512
#define OFF_WIH1T (OFF_WHH0T + 65536)  // 128*512
#define OFF_WHH1T (OFF_WIH1T + 65536)  // 128*512
#define OFF_W0T   (OFF_WHH1T + 65536)  // 5*512
#define OFF_B0    (OFF_W0T + 2560)     // 512
#define OFF_B1    (OFF_B0 + 512)       // 512
#define OFF_A     (OFF_B1 + 512)       // 2500
#define OFF_W1T   (OFF_A + 2500 + 4)   // 2500*256  (pad 4 keeps 16B align: 202692+4... keep %4==0)
#define OFF_FS    (OFF_W1T + 640000)   // 512 feat_sum
#define OFF_NO    (OFF_FS + 512)       // 512*2500
#define OFF_MEANS (OFF_NO + 1280000)   // 512*4
#define OFF_H1    (OFF_MEANS + 2048)   // 512*256
#define WS_FLOATS (OFF_H1 + 131072)

#define PREP_TOTAL (65536*3 + 2560 + 512 + 512 + 2500 + 640000)

__device__ __forceinline__ float sigf(float x) {
    return 1.0f / (1.0f + __expf(-x));
}
__device__ __forceinline__ float tanh_fast(float x) {
    float t = __expf(-2.0f * fabsf(x));
    float r = (1.0f - t) / (1.0f + t);
    return copysignf(r, x);
}

// ---------------------------------------------------------------------------
// K0: prep — transposes, bias folds, a[n] = (sum_k conn_w[n,k]) * sens[n]
// ---------------------------------------------------------------------------
__global__ __launch_bounds__(256) void prep_kernel(
    const float* __restrict__ W_ih0, const float* __restrict__ W_hh0,
    const float* __restrict__ b_ih0, const float* __restrict__ b_hh0,
    const float* __restrict__ W_ih1, const float* __restrict__ W_hh1,
    const float* __restrict__ b_ih1, const float* __restrict__ b_hh1,
    const float* __restrict__ conn_w, const float* __restrict__ sens,
    const float* __restrict__ int_w1,
    float* __restrict__ ws)
{
    int i = blockIdx.x * 256 + threadIdx.x;
    if (i >= PREP_TOTAL) return;

    if (i < 65536) {                       // Whh0T[k][j] = W_hh0[j][k]
        int k = i >> 9, j = i & 511;
        ws[OFF_WHH0T + i] = W_hh0[j * HH + k];
    } else if (i < 131072) {               // Wih1T
        int v = i - 65536;
        int k = v >> 9, j = v & 511;
        ws[OFF_WIH1T + v] = W_ih1[j * HH + k];
    } else if (i < 196608) {               // Whh1T
        int v = i - 131072;
        int k = v >> 9, j = v & 511;
        ws[OFF_WHH1T + v] = W_hh1[j * HH + k];
    } else if (i < 199168) {               // W0T[f][j] = W_ih0[j][f]
        int v = i - 196608;
        int f = v >> 9, j = v & 511;
        ws[OFF_W0T + v] = W_ih0[j * FF + f];
    } else if (i < 199680) {               // b0 = b_ih0 + b_hh0
        int j = i - 199168;
        ws[OFF_B0 + j] = b_ih0[j] + b_hh0[j];
    } else if (i < 200192) {               // b1
        int j = i - 199680;
        ws[OFF_B1 + j] = b_ih1[j] + b_hh1[j];
    } else if (i < 202692) {               // a[n]
        int n = i - 200192;
        float s = 0.f;
        const float* cw = conn_w + n * KK;
        for (int k = 0; k < KK; ++k) s += cw[k];
        ws[OFF_A + n] = s * sens[n];
    } else {                               // w1T[n][m] = int_w1[m][n]
        int v = i - 202692;
        int n = v >> 8, m = v & 255;
        ws[OFF_W1T + v] = int_w1[m * NN + n];
    }
}

// ---------------------------------------------------------------------------
// K1: fused 2-layer LSTM scan + feature MLP head -> feat_sum[b]
// 128 blocks x 512 threads; 4 batch rows per block.
// Thread j computes gate j for all 4 rows; thread (r,k)=(tid>>7, tid&127)
// owns c0/c1 state for its (row, hidden index).
// h stored k-major x row-minor in LDS so one ds_read_b128 feeds 4 FMAs.
// ---------------------------------------------------------------------------
#define BB 4
__global__ __launch_bounds__(512) void lstm_fused(
    const float* __restrict__ x,        // (512,60,5)
    const float* __restrict__ ws_ro,    // workspace (weights)
    const float* __restrict__ fp_w1, const float* __restrict__ fp_b1,
    const float* __restrict__ fp_w2, const float* __restrict__ fp_b2,
    float* __restrict__ feat_sum)
{
    __shared__ float xs[BB][TT * FF + 4];   // 300 + pad
    __shared__ float h0s[HH * BB];          // [k][r]
    __shared__ float h1s[HH * BB];
    __shared__ float gs[G4 * BB];           // [j][r]
    __shared__ float t1s[BB][64];
    __shared__ float bsum[BB][32];

    const float* w0T   = ws_ro + OFF_W0T;
    const float* whh0T = ws_ro + OFF_WHH0T;
    const float* wih1T = ws_ro + OFF_WIH1T;
    const float* whh1T = ws_ro + OFF_WHH1T;
    const float* b0    = ws_ro + OFF_B0;
    const float* b1    = ws_ro + OFF_B1;

    const int tid = threadIdx.x;
    const int brow = blockIdx.x * BB;

    // load x rows into LDS
    for (int i = tid; i < BB * TT * FF; i += 512) {
        int r = i / (TT * FF), c = i % (TT * FF);
        xs[r][c] = x[(brow + r) * (TT * FF) + c];
    }
    // init h
    h0s[tid] = 0.f;
    h1s[tid] = 0.f;
    float c0 = 0.f, c1 = 0.f;
    const int ur = tid >> 7, uk = tid & 127;

    const float bb0 = b0[tid];
    const float bb1 = b1[tid];
    float w0r[FF];
#pragma unroll
    for (int f = 0; f < FF; ++f) w0r[f] = w0T[f * G4 + tid];

    __syncthreads();

    const float4* h0v = (const float4*)h0s;
    const float4* h1v = (const float4*)h1s;

    for (int t = 0; t < TT; ++t) {
        // ---- layer 0 gates ----
        float a0 = bb0, a1 = bb0, a2 = bb0, a3 = bb0;
#pragma unroll
        for (int f = 0; f < FF; ++f) {
            float w = w0r[f];
            a0 += w * xs[0][t * FF + f];
            a1 += w * xs[1][t * FF + f];
            a2 += w * xs[2][t * FF + f];
            a3 += w * xs[3][t * FF + f];
        }
        {
            const float* wp = whh0T + tid;
#pragma unroll 8
            for (int k = 0; k < HH; ++k) {
                float w = wp[k * G4];
                float4 h4 = h0v[k];
                a0 += w * h4.x; a1 += w * h4.y; a2 += w * h4.z; a3 += w * h4.w;
            }
        }
        ((float4*)gs)[tid] = make_float4(a0, a1, a2, a3);
        __syncthreads();
        {   // update layer-0 state
            float ig = gs[uk * 4 + ur];
            float fg = gs[(128 + uk) * 4 + ur];
            float gg = gs[(256 + uk) * 4 + ur];
            float og = gs[(384 + uk) * 4 + ur];
            c0 = sigf(fg) * c0 + sigf(ig) * tanh_fast(gg);
            h0s[uk * 4 + ur] = sigf(og) * tanh_fast(c0);
        }
        __syncthreads();

        // ---- layer 1 gates ----
        a0 = bb1; a1 = bb1; a2 = bb1; a3 = bb1;
        {
            const float* wp = wih1T + tid;
#pragma unroll 8
            for (int k = 0; k < HH; ++k) {
                float w = wp[k * G4];
                float4 h4 = h0v[k];
                a0 += w * h4.x; a1 += w * h4.y; a2 += w * h4.z; a3 += w * h4.w;
            }
        }
        {
            const float* wp = whh1T + tid;
#pragma unroll 8
            for (int k = 0; k < HH; ++k) {
                float w = wp[k * G4];
                float4 h4 = h1v[k];
                a0 += w * h4.x; a1 += w * h4.y; a2 += w * h4.z; a3 += w * h4.w;
            }
        }
        ((float4*)gs)[tid] = make_float4(a0, a1, a2, a3);
        __syncthreads();
        {   // update layer-1 state
            float ig = gs[uk * 4 + ur];
            float fg = gs[(128 + uk) * 4 + ur];
            float gg = gs[(256 + uk) * 4 + ur];
            float og = gs[(384 + uk) * 4 + ur];
            c1 = sigf(fg) * c1 + sigf(ig) * tanh_fast(gg);
            h1s[uk * 4 + ur] = sigf(og) * tanh_fast(c1);
        }
        __syncthreads();
    }

    // ---- head MLP: t1 = relu(hlast @ fp_w1.T + fp_b1) (64) ----
    if (tid < BB * 64) {
        int r = tid >> 6, m = tid & 63;
        float acc = fp_b1[m];
        const float* wp = fp_w1 + m * HH;
        for (int k = 0; k < HH; ++k) acc += wp[k] * h1s[k * 4 + r];
        t1s[r][m] = fmaxf(acc, 0.f);
    }
    __syncthreads();
    // base = tanh(t1 @ fp_w2.T + fp_b2) (32)
    if (tid < BB * 32) {
        int r = tid >> 5, q = tid & 31;
        float acc = fp_b2[q];
        const float* wp = fp_w2 + q * 64;
        for (int m = 0; m < 64; ++m) acc += wp[m] * t1s[r][m];
        bsum[r][q] = tanh_fast(acc);
    }
    __syncthreads();
    if (tid < BB) {
        float s = 0.f;
        for (int q = 0; q < 32; ++q) s += bsum[tid][q];
        feat_sum[brow + tid] = s;
    }
}

// ---------------------------------------------------------------------------
// K2: neuron activations + group means.  one block per batch row.
// ---------------------------------------------------------------------------
__global__ __launch_bounds__(256) void neuron_kernel(
    const float* __restrict__ feat_sum, const float* __restrict__ a,
    const float* __restrict__ thr,
    float* __restrict__ no, float* __restrict__ means)
{
    const int b = blockIdx.x;
    const float s = feat_sum[b];
    float g0 = 0.f, g1 = 0.f, g2 = 0.f, g3 = 0.f;
    for (int n = threadIdx.x; n < NN; n += 256) {
        float pre = s * a[n];
        float v;
        if (n < O0)        { v = sigf(pre - thr[n]);          g0 += v; }
        else if (n < O1)   { v = tanh_fast(pre);              g1 += v; }
        else if (n < O2)   { v = fmaxf(pre - thr[n], 0.f);    g2 += v; }
        else               { v = sigf(pre);                   g3 += v; }
        no[b * NN + n] = v;
    }
    __shared__ float red[4][256];
    red[0][threadIdx.x] = g0; red[1][threadIdx.x] = g1;
    red[2][threadIdx.x] = g2; red[3][threadIdx.x] = g3;
    __syncthreads();
    if (threadIdx.x < 4) {
        float acc = 0.f;
        for (int i = 0; i < 256; ++i) acc += red[threadIdx.x][i];
        const float inv[4] = {1.f / 800.f, 1.f / 700.f, 1.f / 600.f, 1.f / 400.f};
        means[b * 4 + threadIdx.x] = acc * inv[threadIdx.x];
    }
}

// ---------------------------------------------------------------------------
// K3: h1 = relu(no @ int_w1.T + int_b1)   M=512, N=256, K=2500
// 32x32 tiles, 256 threads, 2x2 per thread.
// ---------------------------------------------------------------------------
__global__ __launch_bounds__(256) void gemm_h1(
    const float* __restrict__ no,      // 512 x 2500
    const float* __restrict__ w1T,     // 2500 x 256
    const float* __restrict__ int_b1,  // 256
    float* __restrict__ h1)            // 512 x 256
{
    __shared__ float As[32][33];
    __shared__ float Bs[32][33];
    const int b0 = blockIdx.x * 32;
    const int m0 = blockIdx.y * 32;
    const int tid = threadIdx.x;
    const int ty = tid >> 4, tx = tid & 15;
    const int li = tid >> 3;            // 0..31
    const int lj = (tid & 7) * 4;       // 0..28 step 4

    float acc00 = 0.f, acc01 = 0.f, acc10 = 0.f, acc11 = 0.f;

    for (int k0 = 0; k0 < NN; k0 += 32) {
        float4 av = make_float4(0.f, 0.f, 0.f, 0.f);
        if (k0 + lj < NN)   // last chunk: only lj==0 valid (2500 = 78*32 + 4)
            av = *(const float4*)(no + (b0 + li) * NN + k0 + lj);
        As[li][lj + 0] = av.x; As[li][lj + 1] = av.y;
        As[li][lj + 2] = av.z; As[li][lj + 3] = av.w;

        float4 wv = make_float4(0.f, 0.f, 0.f, 0.f);
        if (k0 + li < NN)
            wv = *(const float4*)(w1T + (k0 + li) * 256 + m0 + lj);
        Bs[li][lj + 0] = wv.x; Bs[li][lj + 1] = wv.y;
        Bs[li][lj + 2] = wv.z; Bs[li][lj + 3] = wv.w;
        __syncthreads();

#pragma unroll 8
        for (int kk = 0; kk < 32; ++kk) {
            float a0 = As[ty * 2][kk],  a1 = As[ty * 2 + 1][kk];
            float w0 = Bs[kk][tx * 2],  w1 = Bs[kk][tx * 2 + 1];
            acc00 += a0 * w0; acc01 += a0 * w1;
            acc10 += a1 * w0; acc11 += a1 * w1;
        }
        __syncthreads();
    }
    const int bi = b0 + ty * 2, mj = m0 + tx * 2;
    h1[bi * 256 + mj]           = fmaxf(acc00 + int_b1[mj], 0.f);
    h1[bi * 256 + mj + 1]       = fmaxf(acc01 + int_b1[mj + 1], 0.f);
    h1[(bi + 1) * 256 + mj]     = fmaxf(acc10 + int_b1[mj], 0.f);
    h1[(bi + 1) * 256 + mj + 1] = fmaxf(acc11 + int_b1[mj + 1], 0.f);
}

// ---------------------------------------------------------------------------
// K4: tail MLP + output assembly.  one block (1 wave) per batch row.
// out[b][0:3]=trend [3:9]=patt [9:13]=keyl [13]=vol [14]=conf
// [15]=sigmoid(conf) [16:20]=means
// ---------------------------------------------------------------------------
__global__ __launch_bounds__(64) void tail_kernel(
    const float* __restrict__ h1,
    const float* __restrict__ int_w2, const float* __restrict__ int_b2,
    const float* __restrict__ int_w3, const float* __restrict__ int_b3,
    const float* __restrict__ tw, const float* __restrict__ tb,
    const float* __restrict__ pw, const float* __restrict__ pb,
    const float* __restrict__ kw, const float* __restrict__ kb,
    const float* __restrict__ vw, const float* __restrict__ vb,
    const float* __restrict__ cw, const float* __restrict__ cb,
    const float* __restrict__ means,
    float* __restrict__ out)
{
    const int b = blockIdx.x;
    const int lane = threadIdx.x;
    __shared__ float h2s[64];
    __shared__ float ints[32];
    __shared__ float outs[16];

    {
        float acc = int_b2[lane];
        const float* hp = h1 + b * 256;
        const float* wp = int_w2 + lane * 256;
        for (int m = 0; m < 256; ++m) acc += wp[m] * hp[m];
        h2s[lane] = fmaxf(acc, 0.f);
    }
    __syncthreads();
    if (lane < 32) {
        float acc = int_b3[lane];
        const float* wp = int_w3 + lane * 64;
        for (int m = 0; m < 64; ++m) acc += wp[m] * h2s[m];
        ints[lane] = tanh_fast(acc);
    }
    __syncthreads();
    if (lane < 15) {
        const float* wsel; float bsel;
        if (lane < 3)       { wsel = tw + lane * 32;       bsel = tb[lane]; }
        else if (lane < 9)  { wsel = pw + (lane - 3) * 32; bsel = pb[lane - 3]; }
        else if (lane < 13) { wsel = kw + (lane - 9) * 32; bsel = kb[lane - 9]; }
        else if (lane == 13){ wsel = vw;                   bsel = vb[0]; }
        else                { wsel = cw;                   bsel = cb[0]; }
        float acc = bsel;
        for (int q = 0; q < 32; ++q) acc += wsel[q] * ints[q];
        outs[lane] = acc;
    }
    __syncthreads();
    if (lane < 20) {
        float v;
        if (lane < 15)       v = outs[lane];
        else if (lane == 15) v = sigf(outs[14]);
        else                 v = means[b * 4 + (lane - 16)];
        out[b * 20 + lane] = v;
    }
}

// ---------------------------------------------------------------------------
extern "C" void kernel_launch(void* const* d_in, const int* in_sizes, int n_in,
                              void* d_out, int out_size, void* d_ws, size_t ws_size,
                              hipStream_t stream)
{
    const float* x      = (const float*)d_in[0];
    const float* W_ih0  = (const float*)d_in[1];
    const float* W_hh0  = (const float*)d_in[2];
    const float* b_ih0  = (const float*)d_in[3];
    const float* b_hh0  = (const float*)d_in[4];
    const float* W_ih1  = (const float*)d_in[5];
    const float* W_hh1  = (const float*)d_in[6];
    const float* b_ih1  = (const float*)d_in[7];
    const float* b_hh1  = (const float*)d_in[8];
    const float* fp_w1  = (const float*)d_in[9];
    const float* fp_b1  = (const float*)d_in[10];
    const float* fp_w2  = (const float*)d_in[11];
    const float* fp_b2  = (const float*)d_in[12];
    const float* conn_w = (const float*)d_in[13];
    const float* sens   = (const float*)d_in[14];
    const float* thr    = (const float*)d_in[15];
    const float* int_w1 = (const float*)d_in[16];
    const float* int_b1 = (const float*)d_in[17];
    const float* int_w2 = (const float*)d_in[18];
    const float* int_b2 = (const float*)d_in[19];
    const float* int_w3 = (const float*)d_in[20];
    const float* int_b3 = (const float*)d_in[21];
    const float* tw     = (const float*)d_in[22];
    const float* tb     = (const float*)d_in[23];
    const float* pw     = (const float*)d_in[24];
    const float* pb     = (const float*)d_in[25];
    const float* kw     = (const float*)d_in[26];
    const float* kb     = (const float*)d_in[27];
    const float* vw     = (const float*)d_in[28];
    const float* vb     = (const float*)d_in[29];
    const float* cw     = (const float*)d_in[30];
    const float* cb     = (const float*)d_in[31];
    // d_in[32] = conn_idx -- provably unused: acts is feat_sum broadcast.

    float* ws = (float*)d_ws;
    float* out = (float*)d_out;

    // K0: prep
    {
        int blocks = (PREP_TOTAL + 255) / 256;
        prep_kernel<<<blocks, 256, 0, stream>>>(
            W_ih0, W_hh0, b_ih0, b_hh0, W_ih1, W_hh1, b_ih1, b_hh1,
            conn_w, sens, int_w1, ws);
    }
    // K1: fused LSTM scan + feature head
    lstm_fused<<<NB / BB, 512, 0, stream>>>(
        x, ws, fp_w1, fp_b1, fp_w2, fp_b2, ws + OFF_FS);

    // K2: neuron activations + means
    neuron_kernel<<<NB, 256, 0, stream>>>(
        ws + OFF_FS, ws + OFF_A, thr, ws + OFF_NO, ws + OFF_MEANS);

    // K3: integration GEMM
    {
        dim3 grid(NB / 32, 256 / 32);
        gemm_h1<<<grid, 256, 0, stream>>>(
            ws + OFF_NO, ws + OFF_W1T, int_b1, ws + OFF_H1);
    }
    // K4: tail + output
    tail_kernel<<<NB, 64, 0, stream>>>(
        ws + OFF_H1, int_w2, int_b2, int_w3, int_b3,
        tw, tb, pw, pb, kw, kb, vw, vb, cw, cb,
        ws + OFF_MEANS, out);
}